// Round 1
// 197.993 us; speedup vs baseline: 1.4002x; 1.4002x over previous
//
#include <hip/hip_runtime.h>

#define B_  8
#define LV_ 4096
#define D_  256
#define N_  2048
#define P_  32

typedef float v4f __attribute__((ext_vector_type(4)));

__device__ __forceinline__ float lane_bcast_f(float v, int l) {
    return __int_as_float(__builtin_amdgcn_readlane(__float_as_int(v), l));
}

// Pass 1: counting-sort box ids by batch into order[] (d_ws) for XCD-L2 locality.
__global__ __launch_bounds__(256) void build_order_kernel(
    const int* __restrict__ batch_idx, int* __restrict__ order)
{
    __shared__ int cnt[B_], cur[B_];
    const int tid = threadIdx.x;
    if (tid < B_) cnt[tid] = 0;
    __syncthreads();
    for (int n = tid; n < N_; n += 256) atomicAdd(&cnt[batch_idx[n]], 1);
    __syncthreads();
    if (tid == 0) {
        int s = 0;
        for (int b = 0; b < B_; ++b) { cur[b] = s; s += cnt[b]; }
    }
    __syncthreads();
    for (int n = tid; n < N_; n += 256)
        order[atomicAdd(&cur[batch_idx[n]], 1)] = n;
}

// Pass 2: one wave per (box, bin), 4 waves per block.
//
// NEW vs previous version: the per-row weight recurrence (S_prev/gprev, ~24
// VALU ops replicated across all 64 lanes, serial loop -> poor MLP) is
// replaced by a LANE-PARALLEL closed form. With the uniform sample comb
// y_g = a + g*sub (g in [0,gh)), define the prefix area
//   P(t) = sum_{y_g < t} (t - y_g) = n*(t-a) - (sub/2)*n*(n-1),
//   n    = clamp(ceil((t-a)/sub), 0, gh).
// The bilinear (tent) weight of row r is the 2nd difference
//   W(r) = P(r-1) - 2 P(r) + P(r+1),
// with exact clamp overrides:
//   W(0)    = P(1) - P(0)                (low clamp: y<0 samples weight 1)
//   W(LV-1) = cnt + P(LV-2) - P(LV-1)    (hi_case: y>=LV-1 samples weight 1)
// Lane l computes W for row base+l (~35 VALU per 64 rows). The FMA phase
// loads 8 independent rows per group (dwordx4, immediate offsets) and
// broadcasts W_k via v_readlane -> SGPR operand of v_fmac: ~5 VALU/row
// instead of ~24, with 8 loads in flight per wave.
__global__ __launch_bounds__(256) void roi_rows_kernel(
    const float* __restrict__ feat,       // [B, LV, D]
    const float* __restrict__ boxes,      // [N, 2]
    const int*   __restrict__ batch_idx,  // [N]
    const int*   __restrict__ order,      // [N] sorted by batch
    float*       __restrict__ out)        // [N, P, D]
{
    const int slot = (blockIdx.x << 2) + (threadIdx.x >> 6);
    const int n    = order[slot >> 5];
    const int p    = slot & (P_ - 1);
    const int lane = threadIdx.x & 63;

    const float y1    = boxes[2 * n];
    const float y2    = boxes[2 * n + 1];
    const float bin_h = (y2 - y1) * (1.0f / (float)P_);
    const int   gh    = (int)ceilf(bin_h);

    const float4* frow = (const float4*)feat + (long)batch_idx[n] * (LV_ * (D_ / 4)) + lane;

    float accx = 0.f, accy = 0.f, accz = 0.f, accw = 0.f;

    if (gh >= 1) {
        const float cntf    = (float)gh;
        const float sub     = bin_h / cntf;
        const float inv_sub = 1.0f / sub;                  // huge/inf ok: n clamped, NaN killed by fmaxf
        const float halfsub = 0.5f * sub;
        const float boff    = (y1 - 0.5f) + (float)p * bin_h;
        const float a       = fmaf(0.5f, sub, boff);       // first sample
        const float ylast   = fmaf(cntf - 0.5f, sub, boff);

        int r_first = (int)floorf(a);                      // a >= -0.5 so floor >= -1
        if (r_first < 0) r_first = 0;
        if (r_first > LV_ - 1) r_first = LV_ - 1;
        int r_last = (int)floorf(ylast) + 1;
        if (r_last > LV_ - 1) r_last = LV_ - 1;
        if (r_last < r_first) r_last = r_first;

        const float lanef = (float)lane;

        for (int base = r_first; base <= r_last; base += 64) {
            // ---- lane-parallel weights: lane l -> row r = base + l ----
            const int   r  = base + lane;
            const float d0 = ((float)base + lanef) - a;    // box-relative: |d| small -> good precision
            const float dm = d0 - 1.0f;
            const float dp = d0 + 1.0f;

            const float um = dm * inv_sub;
            const float u0 = d0 * inv_sub;
            const float up = dp * inv_sub;
            const float nm = fminf(fmaxf(ceilf(um), 0.0f), cntf);   // fmaxf eats NaN (0*inf)
            const float n0 = fminf(fmaxf(ceilf(u0), 0.0f), cntf);
            const float np = fminf(fmaxf(ceilf(up), 0.0f), cntf);
            float Pm = fmaf(nm, dm, -halfsub * fmaf(nm, nm, -nm));
            float P0 = fmaf(n0, d0, -halfsub * fmaf(n0, n0, -n0));
            float Pp = fmaf(np, dp, -halfsub * fmaf(np, np, -np));
            if (r == 0)       Pm = P0;                      // -> W(0) = P(1)-P(0)
            if (r == LV_ - 1) Pp = P0 + cntf;               // -> W(LV-1) = cnt + P(LV-2)-P(LV-1)
            const float Wl = (Pm + Pp) - 2.0f * P0;
            // lanes with r > r_last hold garbage/zero W; never read below (k <= kmax)

            // ---- FMA phase: 8-row groups, W broadcast via readlane ----
            const int kmax = (r_last - base < 63) ? (r_last - base) : 63;
            const float4* rp = frow + (long)base * (D_ / 4);

            int k = 0;
            for (; k + 8 <= kmax + 1; k += 8) {
                const float4* rk = rp + (long)k * (D_ / 4);
                float4 v[8];
                #pragma unroll
                for (int j = 0; j < 8; ++j) v[j] = rk[j * (D_ / 4)];  // 8 indep loads, imm offsets
                #pragma unroll
                for (int j = 0; j < 8; ++j) {
                    const float w = lane_bcast_f(Wl, k + j);          // SGPR operand for v_fmac
                    accx = fmaf(w, v[j].x, accx);
                    accy = fmaf(w, v[j].y, accy);
                    accz = fmaf(w, v[j].z, accz);
                    accw = fmaf(w, v[j].w, accw);
                }
            }
            for (; k <= kmax; ++k) {                                  // tail rows (0..7)
                const float4 v = rp[(long)k * (D_ / 4)];
                const float w = lane_bcast_f(Wl, k);
                accx = fmaf(w, v.x, accx);
                accy = fmaf(w, v.y, accy);
                accz = fmaf(w, v.z, accz);
                accw = fmaf(w, v.w, accw);
            }
        }
    }

    const float inv_c = 1.0f / (float)(gh > 1 ? gh : 1);
    v4f res;
    res.x = accx * inv_c;
    res.y = accy * inv_c;
    res.z = accz * inv_c;
    res.w = accw * inv_c;
    v4f* op = (v4f*)out + ((long)n * P_ + p) * (D_ / 4) + lane;
    __builtin_nontemporal_store(res, op);
}

extern "C" void kernel_launch(void* const* d_in, const int* in_sizes, int n_in,
                              void* d_out, int out_size, void* d_ws, size_t ws_size,
                              hipStream_t stream) {
    const float* feat      = (const float*)d_in[0];
    const float* boxes     = (const float*)d_in[1];
    const int*   batch_idx = (const int*)d_in[2];
    float*       out       = (float*)d_out;
    int*         order     = (int*)d_ws;    // N_ ints

    build_order_kernel<<<1, 256, 0, stream>>>(batch_idx, order);
    roi_rows_kernel<<<(N_ * P_) / 4, 256, 0, stream>>>(feat, boxes, batch_idx, order, out);
}

// Round 2
// 192.964 us; speedup vs baseline: 1.4367x; 1.0261x over previous
//
#include <hip/hip_runtime.h>

#define B_  8
#define LV_ 4096
#define D_  256
#define N_  2048
#define P_  32

typedef float v4f __attribute__((ext_vector_type(4)));

__device__ __forceinline__ float lane_bcast_f(float v, int l) {
    return __int_as_float(__builtin_amdgcn_readlane(__float_as_int(v), l));
}

// Pass 1: counting-sort box ids by batch into order[] (d_ws) for XCD-L2 locality.
__global__ __launch_bounds__(256) void build_order_kernel(
    const int* __restrict__ batch_idx, int* __restrict__ order)
{
    __shared__ int cnt[B_], cur[B_];
    const int tid = threadIdx.x;
    if (tid < B_) cnt[tid] = 0;
    __syncthreads();
    for (int n = tid; n < N_; n += 256) atomicAdd(&cnt[batch_idx[n]], 1);
    __syncthreads();
    if (tid == 0) {
        int s = 0;
        for (int b = 0; b < B_; ++b) { cur[b] = s; s += cnt[b]; }
    }
    __syncthreads();
    for (int n = tid; n < N_; n += 256)
        order[atomicAdd(&cur[batch_idx[n]], 1)] = n;
}

// Pass 2: one wave per (box, bin), 4 waves per block.
//
// Weight math: lane-parallel closed form (see R1). NEW in R2:
//  (a) XCD-aware bijective block swizzle: HW dispatches consecutive blocks
//      round-robin across the 8 XCDs, so batch-sorted order alone still made
//      every XCD touch all 8 batches (FETCH_SIZE 212MB vs 32MB of feat).
//      swz = (bid&7)*cpx + bid>>3 gives each XCD one contiguous chunk of the
//      sorted order ~= one batch ~= exactly its 4MB L2. nwg=16384, %8==0,
//      so the simple swizzle is bijective.
//  (b) acc/FMA in ext-vector form so the compiler emits v_pk_fma_f32
//      (2 packed ops/row instead of 4 v_fmac).
__global__ __launch_bounds__(256) void roi_rows_kernel(
    const float* __restrict__ feat,       // [B, LV, D]
    const float* __restrict__ boxes,      // [N, 2]
    const int*   __restrict__ batch_idx,  // [N]
    const int*   __restrict__ order,      // [N] sorted by batch
    float*       __restrict__ out)        // [N, P, D]
{
    const int nwg = (N_ * P_) / 4;            // 16384 blocks
    const int cpx = nwg >> 3;                 // 2048 blocks per XCD chunk
    const int bid = blockIdx.x;
    const int swz = (bid & 7) * cpx + (bid >> 3);   // XCD k -> contiguous chunk k

    const int slot = (swz << 2) + (threadIdx.x >> 6);
    const int n    = order[slot >> 5];
    const int p    = slot & (P_ - 1);
    const int lane = threadIdx.x & 63;

    const float y1    = boxes[2 * n];
    const float y2    = boxes[2 * n + 1];
    const float bin_h = (y2 - y1) * (1.0f / (float)P_);
    const int   gh    = (int)ceilf(bin_h);

    const v4f* frow = (const v4f*)feat + (long)batch_idx[n] * (LV_ * (D_ / 4)) + lane;

    v4f acc = {0.f, 0.f, 0.f, 0.f};

    if (gh >= 1) {
        const float cntf    = (float)gh;
        const float sub     = bin_h / cntf;
        const float inv_sub = 1.0f / sub;                  // huge/inf ok: n clamped, NaN killed by fmaxf
        const float halfsub = 0.5f * sub;
        const float boff    = (y1 - 0.5f) + (float)p * bin_h;
        const float a       = fmaf(0.5f, sub, boff);       // first sample
        const float ylast   = fmaf(cntf - 0.5f, sub, boff);

        int r_first = (int)floorf(a);                      // a >= -0.5 so floor >= -1
        if (r_first < 0) r_first = 0;
        if (r_first > LV_ - 1) r_first = LV_ - 1;
        int r_last = (int)floorf(ylast) + 1;
        if (r_last > LV_ - 1) r_last = LV_ - 1;
        if (r_last < r_first) r_last = r_first;

        const float lanef = (float)lane;

        for (int base = r_first; base <= r_last; base += 64) {
            // ---- lane-parallel weights: lane l -> row r = base + l ----
            const int   r  = base + lane;
            const float d0 = ((float)base + lanef) - a;    // box-relative: |d| small -> good precision
            const float dm = d0 - 1.0f;
            const float dp = d0 + 1.0f;

            const float um = dm * inv_sub;
            const float u0 = d0 * inv_sub;
            const float up = dp * inv_sub;
            const float nm = fminf(fmaxf(ceilf(um), 0.0f), cntf);   // fmaxf eats NaN (0*inf)
            const float n0 = fminf(fmaxf(ceilf(u0), 0.0f), cntf);
            const float np = fminf(fmaxf(ceilf(up), 0.0f), cntf);
            float Pm = fmaf(nm, dm, -halfsub * fmaf(nm, nm, -nm));
            float P0 = fmaf(n0, d0, -halfsub * fmaf(n0, n0, -n0));
            float Pp = fmaf(np, dp, -halfsub * fmaf(np, np, -np));
            if (r == 0)       Pm = P0;                      // -> W(0) = P(1)-P(0)
            if (r == LV_ - 1) Pp = P0 + cntf;               // -> W(LV-1) = cnt + P(LV-2)-P(LV-1)
            const float Wl = (Pm + Pp) - 2.0f * P0;
            // lanes with r > r_last hold garbage/zero W; never read below (k <= kmax)

            // ---- FMA phase: 8-row groups, W broadcast via readlane ----
            const int kmax = (r_last - base < 63) ? (r_last - base) : 63;
            const v4f* rp = frow + (long)base * (D_ / 4);

            int k = 0;
            for (; k + 8 <= kmax + 1; k += 8) {
                const v4f* rk = rp + (long)k * (D_ / 4);
                v4f v[8];
                #pragma unroll
                for (int j = 0; j < 8; ++j) v[j] = rk[j * (D_ / 4)];  // 8 indep loads in flight
                #pragma unroll
                for (int j = 0; j < 8; ++j) {
                    const float w = lane_bcast_f(Wl, k + j);          // uniform operand for pk_fma
                    acc += v[j] * w;                                  // 2x v_pk_fma_f32
                }
            }
            for (; k <= kmax; ++k) {                                  // tail rows (0..7)
                const v4f v = rp[(long)k * (D_ / 4)];
                const float w = lane_bcast_f(Wl, k);
                acc += v * w;
            }
        }
    }

    const float inv_c = 1.0f / (float)(gh > 1 ? gh : 1);
    v4f res = acc * inv_c;
    v4f* op = (v4f*)out + ((long)n * P_ + p) * (D_ / 4) + lane;
    __builtin_nontemporal_store(res, op);
}

extern "C" void kernel_launch(void* const* d_in, const int* in_sizes, int n_in,
                              void* d_out, int out_size, void* d_ws, size_t ws_size,
                              hipStream_t stream) {
    const float* feat      = (const float*)d_in[0];
    const float* boxes     = (const float*)d_in[1];
    const int*   batch_idx = (const int*)d_in[2];
    float*       out       = (float*)d_out;
    int*         order     = (int*)d_ws;    // N_ ints

    build_order_kernel<<<1, 256, 0, stream>>>(batch_idx, order);
    roi_rows_kernel<<<(N_ * P_) / 4, 256, 0, stream>>>(feat, boxes, batch_idx, order, out);
}